// Round 2
// baseline (170.053 us; speedup 1.0000x reference)
//
#include <hip/hip_runtime.h>

#define BB 2
#define NN 2048
#define EE 768
#define HH 12
#define DD 64
#define MM (BB*NN)      // 4096
#define E3 (3*EE)       // 2304
// 1/sqrt(768) * log2(e): scores in log2 domain -> P = exp2(s)
#define QSCALE 0.05205877280961602f

typedef __bf16 bf16x8 __attribute__((ext_vector_type(8)));
typedef float  f32x4  __attribute__((ext_vector_type(4)));
typedef unsigned short u16x8 __attribute__((ext_vector_type(8)));

#define MFMA(a,b,c) __builtin_amdgcn_mfma_f32_16x16x32_bf16(a,b,c,0,0,0)

__device__ __forceinline__ unsigned short f2bf(float f) {
    unsigned int u = __float_as_uint(f);
    u += 0x7FFFu + ((u >> 16) & 1u);     // round-to-nearest-even
    return (unsigned short)(u >> 16);
}

typedef __attribute__((address_space(3))) unsigned int as3u32;
typedef __attribute__((address_space(1))) unsigned int as1u32;
__device__ __forceinline__ void gll16(const void* g, void* l) {
    // lane i deposits its 16B at lds_base + i*16 (wave-uniform dest base)
    __builtin_amdgcn_global_load_lds((const as1u32*)(uintptr_t)g,
                                     (as3u32*)(unsigned int)(uintptr_t)l, 16, 0, 0);
}

// ---------------------------------------------------------------------------
// fused f32 -> bf16 cast of x, w_qkv, w_o (contiguous dsts in ws)
// ---------------------------------------------------------------------------
#define XB4 786432   // (MM*EE)/4
#define WQ4 442368   // (E3*EE)/4
#define WO4 147456   // (EE*EE)/4
__global__ __launch_bounds__(256)
void cast3(const float* __restrict__ x, const float* __restrict__ wq,
           const float* __restrict__ wo, unsigned short* __restrict__ dst) {
    int i = blockIdx.x * 256 + threadIdx.x;
    const float* src;
    int off;
    if (i < XB4)            { src = x;  off = i; }
    else if (i < XB4+WQ4)   { src = wq; off = i - XB4; }
    else                    { src = wo; off = i - XB4 - WQ4; }
    float4 v = ((const float4*)src)[off];
    ushort4 o;
    o.x = f2bf(v.x); o.y = f2bf(v.y); o.z = f2bf(v.z); o.w = f2bf(v.w);
    ((ushort4*)dst)[i] = o;
}

// ---------------------------------------------------------------------------
// QKV GEMM: 128x64 tile, BK=32, 4 waves, wave tile 64x32 (4x2 frags).
// Grid (32,36) = 1152 blocks = 4.5 blocks/CU.
// Each block covers exactly one (h,t) 64-col section.
// Scatter: q (scaled) [B][H][N][D], k [B][H][N][D], v transposed [B][H][D][N].
// ---------------------------------------------------------------------------
__global__ __launch_bounds__(256)
void gemm_qkv(const unsigned short* __restrict__ A, const unsigned short* __restrict__ W,
              const float* __restrict__ bias,
              unsigned short* __restrict__ o0, unsigned short* __restrict__ o1,
              unsigned short* __restrict__ o2)
{
    __shared__ unsigned short As[128 * 32];   // 8 KB
    __shared__ unsigned short Bs[64 * 32];    // 4 KB

    const int tid = threadIdx.x;
    const int l = tid & 63;
    const int w = tid >> 6;
    const int m0 = blockIdx.x * 128;
    const int c0 = blockIdx.y * 64;
    const int wm = (w >> 1) * 64;
    const int wn = (w & 1) * 32;

    // staging: 12 chunks of 16 rows x 32 k (8 A + 4 B); wave stages 3w..3w+2
    const unsigned short* s_src[3];
    unsigned short* s_dst[3];
    #pragma unroll
    for (int s = 0; s < 3; ++s) {
        const int ch = 3*w + s;
        if (ch < 8) {
            s_src[s] = A + (size_t)(m0 + ch*16 + (l>>2)) * EE + (l&3)*8;
            s_dst[s] = &As[ch*512];
        } else {
            s_src[s] = W + (size_t)(c0 + (ch-8)*16 + (l>>2)) * EE + (l&3)*8;
            s_dst[s] = &Bs[(ch-8)*512];
        }
    }

    const f32x4 zero4 = {0.f, 0.f, 0.f, 0.f};
    f32x4 acc[4][2];
    #pragma unroll
    for (int i = 0; i < 4; ++i)
        #pragma unroll
        for (int j = 0; j < 2; ++j) acc[i][j] = zero4;

    for (int k0 = 0; k0 < EE; k0 += 32) {
        __syncthreads();
        #pragma unroll
        for (int s = 0; s < 3; ++s) gll16(s_src[s] + k0, s_dst[s]);
        __syncthreads();

        bf16x8 af[4], bf[2];
        #pragma unroll
        for (int i = 0; i < 4; ++i)
            af[i] = *(const bf16x8*)&As[(wm + 16*i + (l&15))*32 + (l>>4)*8];
        #pragma unroll
        for (int j = 0; j < 2; ++j)
            bf[j] = *(const bf16x8*)&Bs[(wn + 16*j + (l&15))*32 + (l>>4)*8];
        #pragma unroll
        for (int i = 0; i < 4; ++i)
            #pragma unroll
            for (int j = 0; j < 2; ++j)
                acc[i][j] = MFMA(af[i], bf[j], acc[i][j]);
    }

    // epilogue: C/D col = l&15, row = (l>>4)*4 + r. Block = one (h,t) section.
    const int sec = c0 >> 6;               // = hh*3 + tt
    const int hh = sec / 3;
    const int tt = sec - hh*3;
    #pragma unroll
    for (int j = 0; j < 2; ++j) {
        const int col = c0 + wn + 16*j + (l&15);
        const int dcol = wn + 16*j + (l&15);   // 0..63 within section
        const float bj = bias[col];
        #pragma unroll
        for (int i = 0; i < 4; ++i) {
            const int row0 = m0 + wm + 16*i + (l>>4)*4;
            const int b = row0 >> 11;
            const int n = row0 & (NN - 1);
            if (tt == 2) {
                ushort4 pk;
                pk.x = f2bf(acc[i][j][0] + bj);
                pk.y = f2bf(acc[i][j][1] + bj);
                pk.z = f2bf(acc[i][j][2] + bj);
                pk.w = f2bf(acc[i][j][3] + bj);
                *(ushort4*)&o2[(((size_t)b*HH + hh)*DD + dcol)*NN + n] = pk;
            } else {
                unsigned short* dst = (tt == 0) ? o0 : o1;
                #pragma unroll
                for (int r = 0; r < 4; ++r) {
                    float val = acc[i][j][r] + bj;
                    if (tt == 0) val *= QSCALE;
                    dst[(((size_t)b*HH + hh)*NN + n + r)*DD + dcol] = f2bf(val);
                }
            }
        }
    }
}

// ---------------------------------------------------------------------------
// Output GEMM: 64x64 tile, BK=32, 4 waves, wave tile 32x32 (2x2 frags).
// Grid (64,12) = 768 blocks = 3 blocks/CU.
// ---------------------------------------------------------------------------
__global__ __launch_bounds__(256)
void gemm_out(const unsigned short* __restrict__ A, const unsigned short* __restrict__ W,
              const float* __restrict__ bias, float* __restrict__ of)
{
    __shared__ unsigned short As[64 * 32];    // 4 KB
    __shared__ unsigned short Bs[64 * 32];    // 4 KB

    const int tid = threadIdx.x;
    const int l = tid & 63;
    const int w = tid >> 6;
    const int m0 = blockIdx.x * 64;
    const int c0 = blockIdx.y * 64;
    const int wm = (w >> 1) * 32;
    const int wn = (w & 1) * 32;

    // staging: 8 chunks of 16 rows x 32 k (4 A + 4 B); wave stages 2w, 2w+1
    const unsigned short* s_src[2];
    unsigned short* s_dst[2];
    #pragma unroll
    for (int s = 0; s < 2; ++s) {
        const int ch = 2*w + s;
        if (ch < 4) {
            s_src[s] = A + (size_t)(m0 + ch*16 + (l>>2)) * EE + (l&3)*8;
            s_dst[s] = &As[ch*512];
        } else {
            s_src[s] = W + (size_t)(c0 + (ch-4)*16 + (l>>2)) * EE + (l&3)*8;
            s_dst[s] = &Bs[(ch-4)*512];
        }
    }

    const f32x4 zero4 = {0.f, 0.f, 0.f, 0.f};
    f32x4 acc[2][2];
    #pragma unroll
    for (int i = 0; i < 2; ++i)
        #pragma unroll
        for (int j = 0; j < 2; ++j) acc[i][j] = zero4;

    for (int k0 = 0; k0 < EE; k0 += 32) {
        __syncthreads();
        #pragma unroll
        for (int s = 0; s < 2; ++s) gll16(s_src[s] + k0, s_dst[s]);
        __syncthreads();

        bf16x8 af[2], bf[2];
        #pragma unroll
        for (int i = 0; i < 2; ++i)
            af[i] = *(const bf16x8*)&As[(wm + 16*i + (l&15))*32 + (l>>4)*8];
        #pragma unroll
        for (int j = 0; j < 2; ++j)
            bf[j] = *(const bf16x8*)&Bs[(wn + 16*j + (l&15))*32 + (l>>4)*8];
        #pragma unroll
        for (int i = 0; i < 2; ++i)
            #pragma unroll
            for (int j = 0; j < 2; ++j)
                acc[i][j] = MFMA(af[i], bf[j], acc[i][j]);
    }

    #pragma unroll
    for (int j = 0; j < 2; ++j) {
        const int col = c0 + wn + 16*j + (l&15);
        const float bj = bias[col];
        #pragma unroll
        for (int i = 0; i < 2; ++i) {
            #pragma unroll
            for (int r = 0; r < 4; ++r) {
                const int row = m0 + wm + 16*i + (l>>4)*4 + r;
                of[(size_t)row * EE + col] = acc[i][j][r] + bj;
            }
        }
    }
}

// ---------------------------------------------------------------------------
// MFMA flash attention, v3: r10 structure + T14 async-STAGE pipeline.
// (v2's cvt_pk_bf16 reverted: suspected non-RNE rounding -> absmax 2.4e-2.
//  f2bf bit-trick is exactly RNE and matched the reference at 5.5e-4.)
//   - K/V tile kt+1's global loads are issued RIGHT AFTER tile kt's LDS
//     writes and stay in flight across the barrier and under tile kt's
//     compute (barriers are raw s_barrier + lgkmcnt(0) only — NO vmcnt
//     drain, unlike __syncthreads). The ds_writes of tile kt+1 then pick
//     up the landed registers (compiler inserts the counted vmcnt there).
// Block = 64 Q of one (b,h), 4 waves x 16 q. Grid 768: bh = id%24.
// S^T = K*Q^T, per-lane no-max softmax, deferred denominator.
// Ks/Vt: per half [row][64], 16B-chunk ^ (row&7); Pq per-wave per-half,
// 8B-chunk ^ (q&14). LDS 48 KB -> 3 blocks/CU.
// ---------------------------------------------------------------------------
struct KVT { u16x8 k0, k1, k2, k3, v0, v1, v2, v3; };

__global__ __launch_bounds__(256)
void attn_mfma(const unsigned short* __restrict__ Q, const unsigned short* __restrict__ K,
               const unsigned short* __restrict__ Vt_g, unsigned short* __restrict__ ctx)
{
    __shared__ unsigned short Ks[2 * 64 * 64];       // 16 KB (two halves)
    __shared__ unsigned short Vt[2 * 64 * 64];       // 16 KB
    __shared__ unsigned short Pq[4 * 2 * 16 * 64];   // 16 KB, [wave][half][q][64]

    const int tid = threadIdx.x;
    const int l = tid & 63;
    const int w = tid >> 6;
    const int quad = l >> 4;
    const int lc = l & 15;
    const int x7 = lc & 7;

    const int id = blockIdx.x;
    const int bh = id % 24;              // b*HH + h
    const int bq = id / 24;              // q-tile
    const int b  = bh / 12;
    const int h  = bh - b*12;
    const size_t hb = (size_t)bh * NN * DD;

    const f32x4 zero4 = {0.f, 0.f, 0.f, 0.f};

    // Q B-frags (pre-scaled by QSCALE): B[n=q=lc][k=d=quad*8+j]
    const int qrow = bq*64 + w*16 + lc;
    const bf16x8 qf0 = *(const bf16x8*)(Q + hb + (size_t)qrow*DD +      quad*8);
    const bf16x8 qf1 = *(const bf16x8*)(Q + hb + (size_t)qrow*DD + 32 + quad*8);

    f32x4 o[4];
    #pragma unroll
    for (int dj = 0; dj < 4; ++dj) o[dj] = zero4;
    float lsum = 0.f;

    // staging: 256 threads, row = tid>>2 (64 rows/half), sc = tid&3 (2 chunks)
    const int srow = tid >> 2;
    const int sc = tid & 3;
    const unsigned short* kbase = K + hb + (size_t)srow*DD + sc*16;
    const unsigned short* vbase = Vt_g + hb + (size_t)srow*NN + sc*16;
    const int c0s = ((2*sc)     ^ (srow & 7)) * 8;
    const int c1s = ((2*sc + 1) ^ (srow & 7)) * 8;
    const int so = srow * 64;

    // frag-read swizzled chunk offsets (same for both halves)
    const int chq0 = ((    quad) ^ x7) * 8;
    const int chq1 = ((4 + quad) ^ x7) * 8;
    const int pw = w * 2048;
    const int prd0 = lc*64 + (((    2*quad) ^ (lc & 14)) * 4);
    const int prd1 = lc*64 + (((8 + 2*quad) ^ (lc & 14)) * 4);

    auto loadt = [&](KVT& R, int kt) {
        const unsigned short* k0p = kbase + (size_t)kt*128*DD;
        const unsigned short* v0p = vbase + kt*128;
        R.k0 = *(const u16x8*)k0p;
        R.k1 = *(const u16x8*)(k0p + 8);
        R.k2 = *(const u16x8*)(k0p + (size_t)64*DD);
        R.k3 = *(const u16x8*)(k0p + (size_t)64*DD + 8);
        R.v0 = *(const u16x8*)v0p;
        R.v1 = *(const u16x8*)(v0p + 8);
        R.v2 = *(const u16x8*)(v0p + 64);
        R.v3 = *(const u16x8*)(v0p + 64 + 8);
    };

    auto step = [&](KVT& CUR, KVT& NXT, int kt) {
        // bar A: all waves finished READING the previous tile's LDS.
        // lgkmcnt(0) only — any in-flight global prefetch stays in flight.
        asm volatile("s_waitcnt lgkmcnt(0)" ::: "memory");
        __builtin_amdgcn_s_barrier();

        // write tile kt (vmcnt waits on CUR's regs are inserted here by the
        // compiler — the load latency was hidden under tile kt-1's compute)
        *(u16x8*)&Ks[so + c0s]        = CUR.k0;
        *(u16x8*)&Ks[so + c1s]        = CUR.k1;
        *(u16x8*)&Ks[4096 + so + c0s] = CUR.k2;
        *(u16x8*)&Ks[4096 + so + c1s] = CUR.k3;
        *(u16x8*)&Vt[so + c0s]        = CUR.v0;
        *(u16x8*)&Vt[so + c1s]        = CUR.v1;
        *(u16x8*)&Vt[4096 + so + c0s] = CUR.v2;
        *(u16x8*)&Vt[4096 + so + c1s] = CUR.v3;

        // issue tile kt+1's global loads NOW — they fly under the compute
        if (kt + 1 < NN/128) loadt(NXT, kt + 1);

        // bar B: ds_writes visible to all waves; NO vmcnt drain.
        asm volatile("s_waitcnt lgkmcnt(0)" ::: "memory");
        __builtin_amdgcn_s_barrier();
        __builtin_amdgcn_sched_barrier(0);

        #pragma unroll
        for (int hf = 0; hf < 2; ++hf) {
            const int base = hf * 4096;
            const int pb = pw + hf * 1024;

            // S^T = K Q^T : 4 key-frags x 2 k-steps
            f32x4 st[4];
            #pragma unroll
            for (int jf = 0; jf < 4; ++jf) {
                bf16x8 kf0 = *(const bf16x8*)&Ks[base + (16*jf + lc)*64 + chq0];
                bf16x8 kf1 = *(const bf16x8*)&Ks[base + (16*jf + lc)*64 + chq1];
                f32x4 acc0 = MFMA(kf0, qf0, zero4);
                st[jf] = MFMA(kf1, qf1, acc0);
            }

            // P = exp2(S^T). Lane holds keys 16*jf + quad*4 + r, q = lc.
            #pragma unroll
            for (int jf = 0; jf < 4; ++jf) {
                float e0 = __builtin_amdgcn_exp2f(st[jf][0]);
                float e1 = __builtin_amdgcn_exp2f(st[jf][1]);
                float e2 = __builtin_amdgcn_exp2f(st[jf][2]);
                float e3 = __builtin_amdgcn_exp2f(st[jf][3]);
                lsum += (e0 + e1) + (e2 + e3);
                ushort4 pk;
                pk.x = f2bf(e0); pk.y = f2bf(e1); pk.z = f2bf(e2); pk.w = f2bf(e3);
                *(ushort4*)&Pq[pb + lc*64 + (((4*jf + quad) ^ (lc & 14)) * 4)] = pk;
            }

            // O^T += V^T P^T
            bf16x8 pf0 = *(const bf16x8*)&Pq[pb + prd0];
            bf16x8 pf1 = *(const bf16x8*)&Pq[pb + prd1];
            #pragma unroll
            for (int dj = 0; dj < 4; ++dj) {
                bf16x8 vf0 = *(const bf16x8*)&Vt[base + (16*dj + lc)*64 + chq0];
                bf16x8 vf1 = *(const bf16x8*)&Vt[base + (16*dj + lc)*64 + chq1];
                o[dj] = MFMA(vf0, pf0, o[dj]);
                o[dj] = MFMA(vf1, pf1, o[dj]);
            }
        }
    };

    KVT ra, rb;
    loadt(ra, 0);
    for (int it = 0; it < NN/256; ++it) {   // 8 iters, 2 tiles each
        step(ra, rb, 2*it);
        step(rb, ra, 2*it + 1);
    }

    // final denominator: reduce across the 4 quads (same q = lc)
    lsum += __shfl_xor(lsum, 16);
    lsum += __shfl_xor(lsum, 32);
    const float inv = 1.f / lsum;

    // O^T C-layout: row = d = 16*dj + quad*4 + r, col = q = lc -> packed store
    const int n = bq*64 + w*16 + lc;
    #pragma unroll
    for (int dj = 0; dj < 4; ++dj) {
        ushort4 pk;
        pk.x = f2bf(o[dj][0] * inv);
        pk.y = f2bf(o[dj][1] * inv);
        pk.z = f2bf(o[dj][2] * inv);
        pk.w = f2bf(o[dj][3] * inv);
        *(ushort4*)&ctx[((size_t)(b*NN + n))*EE + h*DD + 16*dj + quad*4] = pk;
    }
}

// ---------------------------------------------------------------------------
extern "C" void kernel_launch(void* const* d_in, const int* in_sizes, int n_in,
                              void* d_out, int out_size, void* d_ws, size_t ws_size,
                              hipStream_t stream)
{
    const float* x     = (const float*)d_in[0];
    const float* w_qkv = (const float*)d_in[1];
    const float* b_qkv = (const float*)d_in[2];
    const float* w_o   = (const float*)d_in[3];
    const float* b_o   = (const float*)d_in[4];
    float* out = (float*)d_out;

    unsigned short* wsu = (unsigned short*)d_ws;
    const size_t XB = (size_t)MM * EE;
    const size_t WQ = (size_t)E3 * EE;
    const size_t WO = (size_t)EE * EE;
    const size_t HS = (size_t)BB * HH * NN * DD;
    unsigned short* xb   = wsu;
    unsigned short* wqb  = xb  + XB;
    unsigned short* wob  = wqb + WQ;
    unsigned short* qb   = wob + WO;      // [B][H][N][D] (scaled)
    unsigned short* kb   = qb  + HS;      // [B][H][N][D]
    unsigned short* vtb  = kb  + HS;      // [B][H][D][N]
    unsigned short* ctxb = vtb + HS;

    cast3<<<(XB4 + WQ4 + WO4)/256, 256, 0, stream>>>(x, w_qkv, w_o, xb);

    dim3 g1(MM/128, E3/64);    // 32 x 36 = 1152 blocks
    gemm_qkv<<<g1, 256, 0, stream>>>(xb, wqb, b_qkv, qb, kb, vtb);

    attn_mfma<<<768, 256, 0, stream>>>(qb, kb, vtb, ctxb);

    dim3 g3(MM/64, EE/64);     // 64 x 12 = 768 blocks
    gemm_out<<<g3, 256, 0, stream>>>(ctxb, wob, b_o, out);
}

// Round 3
// 168.490 us; speedup vs baseline: 1.0093x; 1.0093x over previous
//
#include <hip/hip_runtime.h>

#define BB 2
#define NN 2048
#define EE 768
#define HH 12
#define DD 64
#define MM (BB*NN)      // 4096
#define E3 (3*EE)       // 2304
// 1/sqrt(768) * log2(e): scores in log2 domain -> P = exp2(s)
#define QSCALE 0.05205877280961602f

typedef __bf16 bf16x8 __attribute__((ext_vector_type(8)));
typedef float  f32x4  __attribute__((ext_vector_type(4)));
typedef unsigned short u16x8 __attribute__((ext_vector_type(8)));

#define MFMA(a,b,c) __builtin_amdgcn_mfma_f32_16x16x32_bf16(a,b,c,0,0,0)

__device__ __forceinline__ unsigned short f2bf(float f) {
    unsigned int u = __float_as_uint(f);
    u += 0x7FFFu + ((u >> 16) & 1u);     // round-to-nearest-even
    return (unsigned short)(u >> 16);
}

__device__ __forceinline__ bf16x8 as_bf16x8(u16x8 v) {
    union { u16x8 u; bf16x8 b; } c; c.u = v; return c.b;
}

typedef __attribute__((address_space(3))) unsigned int as3u32;
typedef __attribute__((address_space(1))) unsigned int as1u32;
__device__ __forceinline__ void gll16(const void* g, void* l) {
    // lane i deposits its 16B at lds_base + i*16 (wave-uniform dest base)
    __builtin_amdgcn_global_load_lds((const as1u32*)(uintptr_t)g,
                                     (as3u32*)(unsigned int)(uintptr_t)l, 16, 0, 0);
}

// ---------------------------------------------------------------------------
// fused f32 -> bf16 cast of x, w_qkv, w_o (contiguous dsts in ws)
// ---------------------------------------------------------------------------
#define XB4 786432   // (MM*EE)/4
#define WQ4 442368   // (E3*EE)/4
#define WO4 147456   // (EE*EE)/4
__global__ __launch_bounds__(256)
void cast3(const float* __restrict__ x, const float* __restrict__ wq,
           const float* __restrict__ wo, unsigned short* __restrict__ dst) {
    int i = blockIdx.x * 256 + threadIdx.x;
    const float* src;
    int off;
    if (i < XB4)            { src = x;  off = i; }
    else if (i < XB4+WQ4)   { src = wq; off = i - XB4; }
    else                    { src = wo; off = i - XB4 - WQ4; }
    float4 v = ((const float4*)src)[off];
    ushort4 o;
    o.x = f2bf(v.x); o.y = f2bf(v.y); o.z = f2bf(v.z); o.w = f2bf(v.w);
    ((ushort4*)dst)[i] = o;
}

// ---------------------------------------------------------------------------
// QKV GEMM: 128x64 tile, BK=32, 4 waves, wave tile 64x32 (4x2 frags).
// Grid (32,36) = 1152 blocks = 4.5 blocks/CU.
// Each block covers exactly one (h,t) 64-col section.
// Scatter: q (scaled) [B][H][N][D], k [B][H][N][D], v transposed [B][H][D][N].
// ---------------------------------------------------------------------------
__global__ __launch_bounds__(256)
void gemm_qkv(const unsigned short* __restrict__ A, const unsigned short* __restrict__ W,
              const float* __restrict__ bias,
              unsigned short* __restrict__ o0, unsigned short* __restrict__ o1,
              unsigned short* __restrict__ o2)
{
    __shared__ unsigned short As[128 * 32];   // 8 KB
    __shared__ unsigned short Bs[64 * 32];    // 4 KB

    const int tid = threadIdx.x;
    const int l = tid & 63;
    const int w = tid >> 6;
    const int m0 = blockIdx.x * 128;
    const int c0 = blockIdx.y * 64;
    const int wm = (w >> 1) * 64;
    const int wn = (w & 1) * 32;

    // staging: 12 chunks of 16 rows x 32 k (8 A + 4 B); wave stages 3w..3w+2
    const unsigned short* s_src[3];
    unsigned short* s_dst[3];
    #pragma unroll
    for (int s = 0; s < 3; ++s) {
        const int ch = 3*w + s;
        if (ch < 8) {
            s_src[s] = A + (size_t)(m0 + ch*16 + (l>>2)) * EE + (l&3)*8;
            s_dst[s] = &As[ch*512];
        } else {
            s_src[s] = W + (size_t)(c0 + (ch-8)*16 + (l>>2)) * EE + (l&3)*8;
            s_dst[s] = &Bs[(ch-8)*512];
        }
    }

    const f32x4 zero4 = {0.f, 0.f, 0.f, 0.f};
    f32x4 acc[4][2];
    #pragma unroll
    for (int i = 0; i < 4; ++i)
        #pragma unroll
        for (int j = 0; j < 2; ++j) acc[i][j] = zero4;

    for (int k0 = 0; k0 < EE; k0 += 32) {
        __syncthreads();
        #pragma unroll
        for (int s = 0; s < 3; ++s) gll16(s_src[s] + k0, s_dst[s]);
        __syncthreads();

        bf16x8 af[4], bf[2];
        #pragma unroll
        for (int i = 0; i < 4; ++i)
            af[i] = *(const bf16x8*)&As[(wm + 16*i + (l&15))*32 + (l>>4)*8];
        #pragma unroll
        for (int j = 0; j < 2; ++j)
            bf[j] = *(const bf16x8*)&Bs[(wn + 16*j + (l&15))*32 + (l>>4)*8];
        #pragma unroll
        for (int i = 0; i < 4; ++i)
            #pragma unroll
            for (int j = 0; j < 2; ++j)
                acc[i][j] = MFMA(af[i], bf[j], acc[i][j]);
    }

    // epilogue: C/D col = l&15, row = (l>>4)*4 + r. Block = one (h,t) section.
    const int sec = c0 >> 6;               // = hh*3 + tt
    const int hh = sec / 3;
    const int tt = sec - hh*3;
    #pragma unroll
    for (int j = 0; j < 2; ++j) {
        const int col = c0 + wn + 16*j + (l&15);
        const int dcol = wn + 16*j + (l&15);   // 0..63 within section
        const float bj = bias[col];
        #pragma unroll
        for (int i = 0; i < 4; ++i) {
            const int row0 = m0 + wm + 16*i + (l>>4)*4;
            const int b = row0 >> 11;
            const int n = row0 & (NN - 1);
            if (tt == 2) {
                ushort4 pk;
                pk.x = f2bf(acc[i][j][0] + bj);
                pk.y = f2bf(acc[i][j][1] + bj);
                pk.z = f2bf(acc[i][j][2] + bj);
                pk.w = f2bf(acc[i][j][3] + bj);
                *(ushort4*)&o2[(((size_t)b*HH + hh)*DD + dcol)*NN + n] = pk;
            } else {
                unsigned short* dst = (tt == 0) ? o0 : o1;
                #pragma unroll
                for (int r = 0; r < 4; ++r) {
                    float val = acc[i][j][r] + bj;
                    if (tt == 0) val *= QSCALE;
                    dst[(((size_t)b*HH + hh)*NN + n + r)*DD + dcol] = f2bf(val);
                }
            }
        }
    }
}

// ---------------------------------------------------------------------------
// Output GEMM: 64x64 tile, BK=32, 4 waves, wave tile 32x32 (2x2 frags).
// Grid (64,12) = 768 blocks = 3 blocks/CU.
// ---------------------------------------------------------------------------
__global__ __launch_bounds__(256)
void gemm_out(const unsigned short* __restrict__ A, const unsigned short* __restrict__ W,
              const float* __restrict__ bias, float* __restrict__ of)
{
    __shared__ unsigned short As[64 * 32];    // 4 KB
    __shared__ unsigned short Bs[64 * 32];    // 4 KB

    const int tid = threadIdx.x;
    const int l = tid & 63;
    const int w = tid >> 6;
    const int m0 = blockIdx.x * 64;
    const int c0 = blockIdx.y * 64;
    const int wm = (w >> 1) * 32;
    const int wn = (w & 1) * 32;

    // staging: 8 chunks of 16 rows x 32 k (4 A + 4 B); wave stages 2w, 2w+1
    const unsigned short* s_src[2];
    unsigned short* s_dst[2];
    #pragma unroll
    for (int s = 0; s < 2; ++s) {
        const int ch = 2*w + s;
        if (ch < 4) {
            s_src[s] = A + (size_t)(m0 + ch*16 + (l>>2)) * EE + (l&3)*8;
            s_dst[s] = &As[ch*512];
        } else {
            s_src[s] = W + (size_t)(c0 + (ch-4)*16 + (l>>2)) * EE + (l&3)*8;
            s_dst[s] = &Bs[(ch-4)*512];
        }
    }

    const f32x4 zero4 = {0.f, 0.f, 0.f, 0.f};
    f32x4 acc[2][2];
    #pragma unroll
    for (int i = 0; i < 2; ++i)
        #pragma unroll
        for (int j = 0; j < 2; ++j) acc[i][j] = zero4;

    for (int k0 = 0; k0 < EE; k0 += 32) {
        __syncthreads();
        #pragma unroll
        for (int s = 0; s < 2; ++s) gll16(s_src[s] + k0, s_dst[s]);
        __syncthreads();

        bf16x8 af[2], bf[2];
        #pragma unroll
        for (int i = 0; i < 2; ++i)
            af[i] = *(const bf16x8*)&As[(wm + 16*i + (l&15))*32 + (l>>4)*8];
        #pragma unroll
        for (int j = 0; j < 2; ++j)
            bf[j] = *(const bf16x8*)&Bs[(wn + 16*j + (l&15))*32 + (l>>4)*8];
        #pragma unroll
        for (int i = 0; i < 2; ++i)
            #pragma unroll
            for (int j = 0; j < 2; ++j)
                acc[i][j] = MFMA(af[i], bf[j], acc[i][j]);
    }

    #pragma unroll
    for (int j = 0; j < 2; ++j) {
        const int col = c0 + wn + 16*j + (l&15);
        const float bj = bias[col];
        #pragma unroll
        for (int i = 0; i < 2; ++i) {
            #pragma unroll
            for (int r = 0; r < 4; ++r) {
                const int row = m0 + wm + 16*i + (l>>4)*4 + r;
                of[(size_t)row * EE + col] = acc[i][j][r] + bj;
            }
        }
    }
}

// ---------------------------------------------------------------------------
// MFMA flash attention, v4: P NEVER LEAVES REGISTERS.
// Key idea: within a PV MFMA the k-dim key order is arbitrary as long as the
// V operand uses the same permutation. Choosing
//     sigma(quad*8+j) = 16*(j>>2) + 4*quad + (j&3)
// makes the required P^T B-frag exactly pack(st[0],st[1]) / pack(st[2],st[3])
// — the e-values the lane already holds. V is staged into LDS with keys
// pre-permuted into matching 16B blocks (pure register shuffle at staging;
// PV read addresses are byte-identical to the old chq0/chq1 reads).
// Removes: Pq LDS (16 KB -> LDS 32 KB), 12 LDS ops/tile, and the serial
// P write->read LDS round-trip from the per-half critical path.
// Keeps v3's async-STAGE pipeline (raw s_barrier + lgkmcnt, no vmcnt drain).
// Block = 64 Q of one (b,h), 4 waves x 16 q. Grid 768: bh = id%24.
// ---------------------------------------------------------------------------
struct KVT { u16x8 k0, k1, k2, k3, v0, v1, v2, v3; };

__global__ __launch_bounds__(256)
void attn_mfma(const unsigned short* __restrict__ Q, const unsigned short* __restrict__ K,
               const unsigned short* __restrict__ Vt_g, unsigned short* __restrict__ ctx)
{
    __shared__ unsigned short Ks[2 * 64 * 64];       // 16 KB (two halves)
    __shared__ unsigned short Vt[2 * 64 * 64];       // 16 KB, key-permuted blocks

    const int tid = threadIdx.x;
    const int l = tid & 63;
    const int w = tid >> 6;
    const int quad = l >> 4;
    const int lc = l & 15;
    const int x7 = lc & 7;

    const int id = blockIdx.x;
    const int bh = id % 24;              // b*HH + h
    const int bq = id / 24;              // q-tile
    const int b  = bh / 12;
    const int h  = bh - b*12;
    const size_t hb = (size_t)bh * NN * DD;

    const f32x4 zero4 = {0.f, 0.f, 0.f, 0.f};

    // Q B-frags (pre-scaled by QSCALE): B[n=q=lc][k=d=quad*8+j]
    const int qrow = bq*64 + w*16 + lc;
    const bf16x8 qf0 = *(const bf16x8*)(Q + hb + (size_t)qrow*DD +      quad*8);
    const bf16x8 qf1 = *(const bf16x8*)(Q + hb + (size_t)qrow*DD + 32 + quad*8);

    f32x4 o[4];
    #pragma unroll
    for (int dj = 0; dj < 4; ++dj) o[dj] = zero4;
    float lsum = 0.f;

    // staging: 256 threads, row = tid>>2 (64 rows/half), sc = tid&3
    // K: natural 16B chunks 2sc, 2sc+1.
    // V: thread builds permuted blocks 2sc (keys {8sc..+3, 16+8sc..+3}) and
    //    2sc+1 (keys {8sc+4..+7, 16+8sc+4..+7}) from two contiguous 16B
    //    loads at keys keyA and keyA+16, where keyA = (sc&1)*8 + (sc>>1)*32.
    const int srow = tid >> 2;
    const int sc = tid & 3;
    const unsigned short* kbase = K + hb + (size_t)srow*DD + sc*16;
    const int keyA = (sc & 1)*8 + (sc >> 1)*32;
    const unsigned short* vbase = Vt_g + hb + (size_t)srow*NN + keyA;
    const int c0s = ((2*sc)     ^ (srow & 7)) * 8;
    const int c1s = ((2*sc + 1) ^ (srow & 7)) * 8;
    const int so = srow * 64;

    // frag-read swizzled chunk offsets (same for both halves)
    const int chq0 = ((    quad) ^ x7) * 8;
    const int chq1 = ((4 + quad) ^ x7) * 8;

    auto loadt = [&](KVT& R, int kt) {
        const unsigned short* k0p = kbase + (size_t)kt*128*DD;
        const unsigned short* v0p = vbase + kt*128;
        R.k0 = *(const u16x8*)k0p;
        R.k1 = *(const u16x8*)(k0p + 8);
        R.k2 = *(const u16x8*)(k0p + (size_t)64*DD);
        R.k3 = *(const u16x8*)(k0p + (size_t)64*DD + 8);
        R.v0 = *(const u16x8*)v0p;            // half1 keys keyA..keyA+7
        R.v1 = *(const u16x8*)(v0p + 16);     // half1 keys keyA+16..+23
        R.v2 = *(const u16x8*)(v0p + 64);     // half2
        R.v3 = *(const u16x8*)(v0p + 64 + 16);
    };

    auto step = [&](KVT& CUR, KVT& NXT, int kt) {
        // bar A: all waves finished READING the previous tile's LDS.
        asm volatile("s_waitcnt lgkmcnt(0)" ::: "memory");
        __builtin_amdgcn_s_barrier();

        // K natural; V assembled into permuted 16B key-blocks:
        // block 2sc = {lo4(v0), lo4(v1)}, block 2sc+1 = {hi4(v0), hi4(v1)}
        u16x8 w0 = __builtin_shufflevector(CUR.v0, CUR.v1, 0,1,2,3, 8,9,10,11);
        u16x8 w1 = __builtin_shufflevector(CUR.v0, CUR.v1, 4,5,6,7, 12,13,14,15);
        u16x8 w2 = __builtin_shufflevector(CUR.v2, CUR.v3, 0,1,2,3, 8,9,10,11);
        u16x8 w3 = __builtin_shufflevector(CUR.v2, CUR.v3, 4,5,6,7, 12,13,14,15);
        *(u16x8*)&Ks[so + c0s]        = CUR.k0;
        *(u16x8*)&Ks[so + c1s]        = CUR.k1;
        *(u16x8*)&Ks[4096 + so + c0s] = CUR.k2;
        *(u16x8*)&Ks[4096 + so + c1s] = CUR.k3;
        *(u16x8*)&Vt[so + c0s]        = w0;
        *(u16x8*)&Vt[so + c1s]        = w1;
        *(u16x8*)&Vt[4096 + so + c0s] = w2;
        *(u16x8*)&Vt[4096 + so + c1s] = w3;

        // issue tile kt+1's global loads NOW — they fly under the compute
        if (kt + 1 < NN/128) loadt(NXT, kt + 1);

        // bar B: ds_writes visible to all waves; NO vmcnt drain.
        asm volatile("s_waitcnt lgkmcnt(0)" ::: "memory");
        __builtin_amdgcn_s_barrier();
        __builtin_amdgcn_sched_barrier(0);

        #pragma unroll
        for (int hf = 0; hf < 2; ++hf) {
            const int base = hf * 4096;

            // S^T = K Q^T : 4 key-frags x 2 k-steps
            f32x4 st[4];
            #pragma unroll
            for (int jf = 0; jf < 4; ++jf) {
                bf16x8 kf0 = *(const bf16x8*)&Ks[base + (16*jf + lc)*64 + chq0];
                bf16x8 kf1 = *(const bf16x8*)&Ks[base + (16*jf + lc)*64 + chq1];
                f32x4 acc0 = MFMA(kf0, qf0, zero4);
                st[jf] = MFMA(kf1, qf1, acc0);
            }

            // P = exp2(S^T) stays in registers. Lane holds keys
            // 16*jf + quad*4 + r for q = lc; pf0 = sigma-order keys 0..31,
            // pf1 = keys 32..63 — exactly pack(st[0],st[1]) / pack(st[2],st[3]).
            f32x4 ev[4];
            #pragma unroll
            for (int jf = 0; jf < 4; ++jf) {
                ev[jf][0] = __builtin_amdgcn_exp2f(st[jf][0]);
                ev[jf][1] = __builtin_amdgcn_exp2f(st[jf][1]);
                ev[jf][2] = __builtin_amdgcn_exp2f(st[jf][2]);
                ev[jf][3] = __builtin_amdgcn_exp2f(st[jf][3]);
                lsum += (ev[jf][0] + ev[jf][1]) + (ev[jf][2] + ev[jf][3]);
            }
            u16x8 p0, p1;
            #pragma unroll
            for (int r = 0; r < 4; ++r) {
                p0[r]     = f2bf(ev[0][r]);
                p0[r + 4] = f2bf(ev[1][r]);
                p1[r]     = f2bf(ev[2][r]);
                p1[r + 4] = f2bf(ev[3][r]);
            }
            const bf16x8 pf0 = as_bf16x8(p0);
            const bf16x8 pf1 = as_bf16x8(p1);

            // O^T += V^T P^T (V in matching sigma-permuted key blocks)
            #pragma unroll
            for (int dj = 0; dj < 4; ++dj) {
                bf16x8 vf0 = *(const bf16x8*)&Vt[base + (16*dj + lc)*64 + chq0];
                bf16x8 vf1 = *(const bf16x8*)&Vt[base + (16*dj + lc)*64 + chq1];
                o[dj] = MFMA(vf0, pf0, o[dj]);
                o[dj] = MFMA(vf1, pf1, o[dj]);
            }
        }
    };

    KVT ra, rb;
    loadt(ra, 0);
    for (int it = 0; it < NN/256; ++it) {   // 8 iters, 2 tiles each
        step(ra, rb, 2*it);
        step(rb, ra, 2*it + 1);
    }

    // final denominator: reduce across the 4 quads (same q = lc)
    lsum += __shfl_xor(lsum, 16);
    lsum += __shfl_xor(lsum, 32);
    const float inv = 1.f / lsum;

    // O^T C-layout: row = d = 16*dj + quad*4 + r, col = q = lc -> packed store
    const int n = bq*64 + w*16 + lc;
    #pragma unroll
    for (int dj = 0; dj < 4; ++dj) {
        ushort4 pk;
        pk.x = f2bf(o[dj][0] * inv);
        pk.y = f2bf(o[dj][1] * inv);
        pk.z = f2bf(o[dj][2] * inv);
        pk.w = f2bf(o[dj][3] * inv);
        *(ushort4*)&ctx[((size_t)(b*NN + n))*EE + h*DD + 16*dj + quad*4] = pk;
    }
}

// ---------------------------------------------------------------------------
extern "C" void kernel_launch(void* const* d_in, const int* in_sizes, int n_in,
                              void* d_out, int out_size, void* d_ws, size_t ws_size,
                              hipStream_t stream)
{
    const float* x     = (const float*)d_in[0];
    const float* w_qkv = (const float*)d_in[1];
    const float* b_qkv = (const float*)d_in[2];
    const float* w_o   = (const float*)d_in[3];
    const float* b_o   = (const float*)d_in[4];
    float* out = (float*)d_out;

    unsigned short* wsu = (unsigned short*)d_ws;
    const size_t XB = (size_t)MM * EE;
    const size_t WQ = (size_t)E3 * EE;
    const size_t WO = (size_t)EE * EE;
    const size_t HS = (size_t)BB * HH * NN * DD;
    unsigned short* xb   = wsu;
    unsigned short* wqb  = xb  + XB;
    unsigned short* wob  = wqb + WQ;
    unsigned short* qb   = wob + WO;      // [B][H][N][D] (scaled)
    unsigned short* kb   = qb  + HS;      // [B][H][N][D]
    unsigned short* vtb  = kb  + HS;      // [B][H][D][N]
    unsigned short* ctxb = vtb + HS;

    cast3<<<(XB4 + WQ4 + WO4)/256, 256, 0, stream>>>(x, w_qkv, w_o, xb);

    dim3 g1(MM/128, E3/64);    // 32 x 36 = 1152 blocks
    gemm_qkv<<<g1, 256, 0, stream>>>(xb, wqb, b_qkv, qb, kb, vtb);

    attn_mfma<<<768, 256, 0, stream>>>(qb, kb, vtb, ctxb);

    dim3 g3(MM/64, EE/64);     // 64 x 12 = 768 blocks
    gemm_out<<<g3, 256, 0, stream>>>(ctxb, wob, b_o, out);
}